// Round 3
// baseline (81825.781 us; speedup 1.0000x reference)
//
#include <hip/hip_runtime.h>
#include <hip/hip_cooperative_groups.h>
#include <cmath>

namespace cg = cooperative_groups;

// Problem constants (from reference): B=64, T=512, I=512, H=1024, L=2
#define B_  64
#define T_  512
#define I_  512
#define H_  1024
#define TI_ (T_ * I_)   // x row pitch per batch (floats)
#define TH_ (T_ * H_)   // h1 row pitch per batch (floats)
#define CK  64          // K-chunk staged per LDS buffer
#define CP  65          // chunk row pitch (pad +1 -> conflict-free lane=b reads)
#define NBLK 256
#define NTHR 256

// FMA over one staged chunk: 3 weight rows (r,z,n-ish), input from LDS [k][b].
// aN is accXN for x-part chunks, accHN for h-part chunks.
__device__ __forceinline__ void chunk_fma(const float* cb, int b,
                                          const float* wr, const float* wz, const float* wn,
                                          float& aR, float& aZ, float& aN)
{
#pragma unroll
  for (int k4 = 0; k4 < CK / 4; ++k4) {
    float4 WR = *(const float4*)(wr + k4 * 4);
    float4 WZ = *(const float4*)(wz + k4 * 4);
    float4 WN = *(const float4*)(wn + k4 * 4);
    float v0 = cb[(k4 * 4 + 0) * CP + b];
    float v1 = cb[(k4 * 4 + 1) * CP + b];
    float v2 = cb[(k4 * 4 + 2) * CP + b];
    float v3 = cb[(k4 * 4 + 3) * CP + b];
    aR = fmaf(WR.x, v0, aR); aZ = fmaf(WZ.x, v0, aZ); aN = fmaf(WN.x, v0, aN);
    aR = fmaf(WR.y, v1, aR); aZ = fmaf(WZ.y, v1, aZ); aN = fmaf(WN.y, v1, aN);
    aR = fmaf(WR.z, v2, aR); aZ = fmaf(WZ.z, v2, aZ); aN = fmaf(WN.z, v2, aN);
    aR = fmaf(WR.w, v3, aR); aZ = fmaf(WZ.w, v3, aZ); aN = fmaf(WN.w, v3, aN);
  }
}

__global__ void __launch_bounds__(NTHR)
gru_fused(const float* __restrict__ x,
          const float* __restrict__ wih0, const float* __restrict__ whh0,
          const float* __restrict__ bih0, const float* __restrict__ bhh0,
          const float* __restrict__ wih1, const float* __restrict__ whh1,
          const float* __restrict__ bih1, const float* __restrict__ bhh1,
          float* __restrict__ h1, float* __restrict__ hb0, float* __restrict__ hb1,
          float* __restrict__ out)
{
  // Double-buffered input-chunk staging: [2][CK rows of k][CP cols of b]
  __shared__ float chunk[2][CK * CP];

  cg::grid_group grid = cg::this_grid();

  const int tid = threadIdx.x;
  const int b   = tid & 63;                                   // lane = batch row
  const int jj  = __builtin_amdgcn_readfirstlane(tid >> 6);   // wave id, uniform
  const int j   = blockIdx.x * 4 + jj;                        // owned h column

  // staging-slot geometry: thread covers 4 (row, q) float4 slots
  const int q4 = (tid & 15) * 4;   // k offset of this thread's float4
  const int r0 = tid >> 4;         // base row (batch) of slot p=0

  for (int layer = 0; layer < 2; ++layer) {
    const int Ki  = layer ? H_ : I_;
    const int NCX = Ki / CK;        // x-part chunk count
    const int NCH = H_ / CK;        // h-part chunk count

    const float* wih = layer ? wih1 : wih0;
    const float* whh = layer ? whh1 : whh0;
    const float* bih = layer ? bih1 : bih0;
    const float* bhh = layer ? bhh1 : bhh0;

    // wave-uniform weight row pointers (rows j, H+j, 2H+j)
    const float* wxr = wih + (size_t)(0 * H_ + j) * Ki;
    const float* wxz = wih + (size_t)(1 * H_ + j) * Ki;
    const float* wxn = wih + (size_t)(2 * H_ + j) * Ki;
    const float* whr = whh + (size_t)(0 * H_ + j) * H_;
    const float* whz = whh + (size_t)(1 * H_ + j) * H_;
    const float* whn = whh + (size_t)(2 * H_ + j) * H_;

    const float bR  = bih[j] + bhh[j];
    const float bZ  = bih[H_ + j] + bhh[H_ + j];
    const float bXN = bih[2 * H_ + j];
    const float bHN = bhh[2 * H_ + j];

    float hreg = 0.0f;  // this thread's h(b, j), lives in a register all scan long

    for (int t = 0; t < T_; ++t) {
      // chunk sources for this step
      const float* xbase  = layer ? h1 : x;          // "input" sequence
      const size_t xpitch = layer ? (size_t)TH_ : (size_t)TI_;
      const int    xoff   = t * (layer ? H_ : I_);
      const float* hbase  = layer ? ((t & 1) ? hb0 : hb1) : h1;  // prev h
      const size_t hpitch = layer ? (size_t)H_ : (size_t)TH_;
      const int    hoff   = layer ? 0 : (t - 1) * H_;

      const int NC = NCX + (t ? NCH : 0);   // t=0: h == 0, skip h chunks

      float accR = bR, accZ = bZ, accXN = bXN, accHN = bHN;

      // per-chunk global float4 for 4 slots (register prefetch)
      float4 pf0, pf1, pf2, pf3;
      {
        const int c = 0;  // c < NCX always (NCX >= 8)
        const float* p = xbase + xoff + c * CK + q4;
        pf0 = *(const float4*)(p + (size_t)(r0 +  0) * xpitch);
        pf1 = *(const float4*)(p + (size_t)(r0 + 16) * xpitch);
        pf2 = *(const float4*)(p + (size_t)(r0 + 32) * xpitch);
        pf3 = *(const float4*)(p + (size_t)(r0 + 48) * xpitch);
      }

      for (int c = 0; c < NC; ++c) {
        float* cbw = chunk[c & 1];
        // write prefetched chunk -> LDS (transposed [k][b], pitch CP)
        cbw[(q4 + 0) * CP + (r0 +  0)] = pf0.x;
        cbw[(q4 + 1) * CP + (r0 +  0)] = pf0.y;
        cbw[(q4 + 2) * CP + (r0 +  0)] = pf0.z;
        cbw[(q4 + 3) * CP + (r0 +  0)] = pf0.w;
        cbw[(q4 + 0) * CP + (r0 + 16)] = pf1.x;
        cbw[(q4 + 1) * CP + (r0 + 16)] = pf1.y;
        cbw[(q4 + 2) * CP + (r0 + 16)] = pf1.z;
        cbw[(q4 + 3) * CP + (r0 + 16)] = pf1.w;
        cbw[(q4 + 0) * CP + (r0 + 32)] = pf2.x;
        cbw[(q4 + 1) * CP + (r0 + 32)] = pf2.y;
        cbw[(q4 + 2) * CP + (r0 + 32)] = pf2.z;
        cbw[(q4 + 3) * CP + (r0 + 32)] = pf2.w;
        cbw[(q4 + 0) * CP + (r0 + 48)] = pf3.x;
        cbw[(q4 + 1) * CP + (r0 + 48)] = pf3.y;
        cbw[(q4 + 2) * CP + (r0 + 48)] = pf3.z;
        cbw[(q4 + 3) * CP + (r0 + 48)] = pf3.w;

        // prefetch next chunk (overlaps with compute below)
        if (c + 1 < NC) {
          const int cn = c + 1;
          const float* p;
          size_t pit;
          if (cn < NCX) { p = xbase + xoff + cn * CK + q4;            pit = xpitch; }
          else          { p = hbase + hoff + (cn - NCX) * CK + q4;    pit = hpitch; }
          pf0 = *(const float4*)(p + (size_t)(r0 +  0) * pit);
          pf1 = *(const float4*)(p + (size_t)(r0 + 16) * pit);
          pf2 = *(const float4*)(p + (size_t)(r0 + 32) * pit);
          pf3 = *(const float4*)(p + (size_t)(r0 + 48) * pit);
        }

        __syncthreads();  // staged chunk visible; prev buffer free

        const float* cb = chunk[c & 1];
        if (c < NCX) {
          chunk_fma(cb, b, wxr + c * CK, wxz + c * CK, wxn + c * CK,
                    accR, accZ, accXN);
        } else {
          const int kk = c - NCX;
          chunk_fma(cb, b, whr + kk * CK, whz + kk * CK, whn + kk * CK,
                    accR, accZ, accHN);
        }
      }

      // gates
      const float r = 1.0f / (1.0f + expf(-accR));
      const float z = 1.0f / (1.0f + expf(-accZ));
      const float n = tanhf(accXN + r * accHN);
      const float hnew = (1.0f - z) * n + z * hreg;
      hreg = hnew;

      if (layer == 0) {
        h1[(size_t)b * TH_ + (size_t)t * H_ + j] = hnew;     // full sequence out
      } else {
        float* wbuf = (t & 1) ? hb1 : hb0;
        wbuf[b * H_ + j] = hnew;
        if (t == T_ - 1) out[b * H_ + j] = hnew;
      }

      grid.sync();  // h(t) globally visible before step t+1 staging
    }
  }
}

extern "C" void kernel_launch(void* const* d_in, const int* in_sizes, int n_in,
                              void* d_out, int out_size, void* d_ws, size_t ws_size,
                              hipStream_t stream)
{
  const float* x    = (const float*)d_in[0];
  const float* wih0 = (const float*)d_in[1];
  const float* whh0 = (const float*)d_in[2];
  const float* bih0 = (const float*)d_in[3];
  const float* bhh0 = (const float*)d_in[4];
  const float* wih1 = (const float*)d_in[5];
  const float* whh1 = (const float*)d_in[6];
  const float* bih1 = (const float*)d_in[7];
  const float* bhh1 = (const float*)d_in[8];
  float* out = (float*)d_out;

  // workspace: h1 (B*T*H) | hb0 (B*H) | hb1 (B*H)   -> ~128.5 MiB of fp32
  float* h1  = (float*)d_ws;
  float* hb0 = h1 + (size_t)B_ * T_ * H_;
  float* hb1 = hb0 + (size_t)B_ * H_;

  void* args[] = { (void*)&x,
                   (void*)&wih0, (void*)&whh0, (void*)&bih0, (void*)&bhh0,
                   (void*)&wih1, (void*)&whh1, (void*)&bih1, (void*)&bhh1,
                   (void*)&h1, (void*)&hb0, (void*)&hb1, (void*)&out };

  hipLaunchCooperativeKernel((const void*)gru_fused,
                             dim3(NBLK), dim3(NTHR), args, 0, stream);
}

// Round 6
// 48034.839 us; speedup vs baseline: 1.7035x; 1.7035x over previous
//
#include <hip/hip_runtime.h>
#include <cmath>

// Problem constants (from reference): B=64, T=512, I=512, H=1024, L=2
#define B_  64
#define T_  512
#define I_  512
#define H_  1024
#define TI_ (T_ * I_)   // x row pitch per batch (floats)
#define TH_ (T_ * H_)   // h1 row pitch per batch (floats)
#define CK  64          // K-chunk staged per LDS buffer
#define CP  65          // chunk row pitch (pad +1 -> conflict-free lane=b reads)
#define NBLK 256
#define NTHR 256

// ---------------- custom split grid barrier (monotonic counter) -------------
// arrive: block-level sync, then thread0 publishes with RELEASE (flushes this
// XCD's dirty L2 so h-writes are visible device-wide).
__device__ __forceinline__ void bar_arrive(unsigned* ctr)
{
  __syncthreads();
  if (threadIdx.x == 0)
    __hip_atomic_fetch_add(ctr, 1u, __ATOMIC_RELEASE, __HIP_MEMORY_SCOPE_AGENT);
}

// wait: thread0 spins with relaxed agent loads (no per-poll invalidate), one
// ACQUIRE load on exit (invalidates stale L1/L2 lines), then block sync.
__device__ __forceinline__ void bar_wait(unsigned* ctr, unsigned target)
{
  if (threadIdx.x == 0) {
    while (__hip_atomic_load(ctr, __ATOMIC_RELAXED, __HIP_MEMORY_SCOPE_AGENT) < target)
      __builtin_amdgcn_s_sleep(1);
    (void)__hip_atomic_load(ctr, __ATOMIC_ACQUIRE, __HIP_MEMORY_SCOPE_AGENT);
  }
  __syncthreads();
}

// ---------------- per-chunk FMA: 3 weight rows, input from LDS [k][b] -------
__device__ __forceinline__ void chunk_fma(const float* cb, int b,
                                          const float* wr, const float* wz, const float* wn,
                                          float& aR, float& aZ, float& aN)
{
#pragma unroll
  for (int k4 = 0; k4 < CK / 4; ++k4) {
    float4 WR = *(const float4*)(wr + k4 * 4);
    float4 WZ = *(const float4*)(wz + k4 * 4);
    float4 WN = *(const float4*)(wn + k4 * 4);
    float v0 = cb[(k4 * 4 + 0) * CP + b];
    float v1 = cb[(k4 * 4 + 1) * CP + b];
    float v2 = cb[(k4 * 4 + 2) * CP + b];
    float v3 = cb[(k4 * 4 + 3) * CP + b];
    aR = fmaf(WR.x, v0, aR); aZ = fmaf(WZ.x, v0, aZ); aN = fmaf(WN.x, v0, aN);
    aR = fmaf(WR.y, v1, aR); aZ = fmaf(WZ.y, v1, aZ); aN = fmaf(WN.y, v1, aN);
    aR = fmaf(WR.z, v2, aR); aZ = fmaf(WZ.z, v2, aZ); aN = fmaf(WN.z, v2, aN);
    aR = fmaf(WR.w, v3, aR); aZ = fmaf(WZ.w, v3, aZ); aN = fmaf(WN.w, v3, aN);
  }
}

__device__ __forceinline__ void stage_store(float* cbw, int q4, int r0,
                                            const float4& pf0, const float4& pf1,
                                            const float4& pf2, const float4& pf3)
{
  cbw[(q4 + 0) * CP + (r0 +  0)] = pf0.x;
  cbw[(q4 + 1) * CP + (r0 +  0)] = pf0.y;
  cbw[(q4 + 2) * CP + (r0 +  0)] = pf0.z;
  cbw[(q4 + 3) * CP + (r0 +  0)] = pf0.w;
  cbw[(q4 + 0) * CP + (r0 + 16)] = pf1.x;
  cbw[(q4 + 1) * CP + (r0 + 16)] = pf1.y;
  cbw[(q4 + 2) * CP + (r0 + 16)] = pf1.z;
  cbw[(q4 + 3) * CP + (r0 + 16)] = pf1.w;
  cbw[(q4 + 0) * CP + (r0 + 32)] = pf2.x;
  cbw[(q4 + 1) * CP + (r0 + 32)] = pf2.y;
  cbw[(q4 + 2) * CP + (r0 + 32)] = pf2.z;
  cbw[(q4 + 3) * CP + (r0 + 32)] = pf2.w;
  cbw[(q4 + 0) * CP + (r0 + 48)] = pf3.x;
  cbw[(q4 + 1) * CP + (r0 + 48)] = pf3.y;
  cbw[(q4 + 2) * CP + (r0 + 48)] = pf3.z;
  cbw[(q4 + 3) * CP + (r0 + 48)] = pf3.w;
}

// Process a contiguous run of nchunks K-chunks from src (per-batch pitch
// `pitch`), double-buffered through LDS with one-chunk-ahead global prefetch.
__device__ __forceinline__ void phase_chunks(float (*chunk)[CK * CP], int nchunks,
                                             const float* src, size_t pitch,
                                             const float* wr, const float* wz, const float* wn,
                                             float& aR, float& aZ, float& aN,
                                             int q4, int r0, int b)
{
  float4 pf0, pf1, pf2, pf3;
  {
    const float* p = src + q4;
    pf0 = *(const float4*)(p + (size_t)(r0 +  0) * pitch);
    pf1 = *(const float4*)(p + (size_t)(r0 + 16) * pitch);
    pf2 = *(const float4*)(p + (size_t)(r0 + 32) * pitch);
    pf3 = *(const float4*)(p + (size_t)(r0 + 48) * pitch);
  }
  for (int c = 0; c < nchunks; ++c) {
    stage_store(chunk[c & 1], q4, r0, pf0, pf1, pf2, pf3);
    if (c + 1 < nchunks) {
      const float* p = src + (c + 1) * CK + q4;
      pf0 = *(const float4*)(p + (size_t)(r0 +  0) * pitch);
      pf1 = *(const float4*)(p + (size_t)(r0 + 16) * pitch);
      pf2 = *(const float4*)(p + (size_t)(r0 + 32) * pitch);
      pf3 = *(const float4*)(p + (size_t)(r0 + 48) * pitch);
    }
    __syncthreads();
    chunk_fma(chunk[c & 1], b, wr + c * CK, wz + c * CK, wn + c * CK, aR, aZ, aN);
  }
}

__global__ void __launch_bounds__(NTHR)
gru_fused(const float* __restrict__ x,
          const float* __restrict__ wih0, const float* __restrict__ whh0,
          const float* __restrict__ bih0, const float* __restrict__ bhh0,
          const float* __restrict__ wih1, const float* __restrict__ whh1,
          const float* __restrict__ bih1, const float* __restrict__ bhh1,
          float* __restrict__ h1, float* __restrict__ hb0, float* __restrict__ hb1,
          unsigned* __restrict__ bar, float* __restrict__ out)
{
  __shared__ float chunk[2][CK * CP];

  const int tid = threadIdx.x;
  const int b   = tid & 63;                                   // lane = batch row
  const int jj  = __builtin_amdgcn_readfirstlane(tid >> 6);   // wave id, uniform
  const int j   = blockIdx.x * 4 + jj;                        // owned h column
  const int q4  = (tid & 15) * 4;                             // staging k offset
  const int r0  = tid >> 4;                                   // staging base row

  for (int layer = 0; layer < 2; ++layer) {
    const int Ki  = layer ? H_ : I_;
    const int NCX = Ki / CK;        // x-part chunks (8 or 16)
    const int NCH = H_ / CK;        // h-part chunks (16)

    const float* wih = layer ? wih1 : wih0;
    const float* whh = layer ? whh1 : whh0;
    const float* bih = layer ? bih1 : bih0;
    const float* bhh = layer ? bhh1 : bhh0;

    const float* wxr = wih + (size_t)(0 * H_ + j) * Ki;
    const float* wxz = wih + (size_t)(1 * H_ + j) * Ki;
    const float* wxn = wih + (size_t)(2 * H_ + j) * Ki;
    const float* whr = whh + (size_t)(0 * H_ + j) * H_;
    const float* whz = whh + (size_t)(1 * H_ + j) * H_;
    const float* whn = whh + (size_t)(2 * H_ + j) * H_;

    const float bR  = bih[j] + bhh[j];
    const float bZ  = bih[H_ + j] + bhh[H_ + j];
    const float bXN = bih[2 * H_ + j];
    const float bHN = bhh[2 * H_ + j];

    float hreg = 0.0f;  // h(b, j) lives in a register for the whole scan

    for (int t = 0; t < T_; ++t) {
      float accR = bR, accZ = bZ, accXN = bXN, accHN = bHN;

      // layer transition: h1 written by other blocks must be visible before
      // layer-1's x-phase reads it.
      if (layer == 1 && t == 0) bar_wait(bar, (unsigned)T_ * NBLK);

      // ---- x-phase: independent of h(t-1); overlaps other blocks' arrival
      const float* xsrc = layer ? (h1 + (size_t)t * H_) : (x + (size_t)t * I_);
      const size_t xpit = layer ? (size_t)TH_ : (size_t)TI_;
      phase_chunks(chunk, NCX, xsrc, xpit, wxr, wxz, wxn,
                   accR, accZ, accXN, q4, r0, b);

      // ---- h-phase: needs all blocks' h(t-1)
      if (t > 0) {
        bar_wait(bar, (unsigned)(layer * T_ + t) * NBLK);
        const float* hsrc = layer ? ((t & 1) ? hb0 : hb1)
                                  : (h1 + (size_t)(t - 1) * H_);
        const size_t hpit = layer ? (size_t)H_ : (size_t)TH_;
        phase_chunks(chunk, NCH, hsrc, hpit, whr, whz, whn,
                     accR, accZ, accHN, q4, r0, b);
      }

      // gates
      const float r = 1.0f / (1.0f + expf(-accR));
      const float z = 1.0f / (1.0f + expf(-accZ));
      const float n = tanhf(accXN + r * accHN);
      const float hnew = (1.0f - z) * n + z * hreg;
      hreg = hnew;

      if (layer == 0) {
        h1[(size_t)b * TH_ + (size_t)t * H_ + j] = hnew;
      } else {
        ((t & 1) ? hb1 : hb0)[b * H_ + j] = hnew;
        if (t == T_ - 1) out[b * H_ + j] = hnew;
      }

      if (!(layer == 1 && t == T_ - 1))
        bar_arrive(bar);
    }
  }
}

extern "C" void kernel_launch(void* const* d_in, const int* in_sizes, int n_in,
                              void* d_out, int out_size, void* d_ws, size_t ws_size,
                              hipStream_t stream)
{
  const float* x    = (const float*)d_in[0];
  const float* wih0 = (const float*)d_in[1];
  const float* whh0 = (const float*)d_in[2];
  const float* bih0 = (const float*)d_in[3];
  const float* bhh0 = (const float*)d_in[4];
  const float* wih1 = (const float*)d_in[5];
  const float* whh1 = (const float*)d_in[6];
  const float* bih1 = (const float*)d_in[7];
  const float* bhh1 = (const float*)d_in[8];
  float* out = (float*)d_out;

  // workspace: h1 (B*T*H) | hb0 (B*H) | hb1 (B*H) | barrier counter
  float* h1  = (float*)d_ws;
  float* hb0 = h1 + (size_t)B_ * T_ * H_;
  float* hb1 = hb0 + (size_t)B_ * H_;
  unsigned* bar = (unsigned*)(hb1 + (size_t)B_ * H_);

  // barrier counter must start at 0 (harness poisons ws with 0xAA)
  hipMemsetAsync(bar, 0, 256, stream);

  void* args[] = { (void*)&x,
                   (void*)&wih0, (void*)&whh0, (void*)&bih0, (void*)&bhh0,
                   (void*)&wih1, (void*)&whh1, (void*)&bih1, (void*)&bhh1,
                   (void*)&h1, (void*)&hb0, (void*)&hb1, (void*)&bar, (void*)&out };

  hipLaunchCooperativeKernel((const void*)gru_fused,
                             dim3(NBLK), dim3(NTHR), args, 0, stream);
}